// Round 14
// baseline (161.933 us; speedup 1.0000x reference)
//
#include <hip/hip_runtime.h>

#define BB  4
#define LL  512
#define HID 256
#define PAi 32
#define OO  64

using bf16x8 = __attribute__((ext_vector_type(8))) short;
using f32x4  = __attribute__((ext_vector_type(4))) float;

__device__ inline ushort f2bf(float x) {
    union { float f; unsigned u; } v; v.f = x;
    unsigned r = (v.u + 0x7fff + ((v.u >> 16) & 1)) >> 16;  // RNE
    return (ushort)r;
}

// Relaxed barrier: order LDS traffic only; global prefetches stay in flight.
__device__ inline void barrier_lds() {
    asm volatile("s_waitcnt lgkmcnt(0)" ::: "memory");
    __builtin_amdgcn_s_barrier();
}

// -------- Kernel 1: h[b,l,p] = dot(hidden[b,l,:], W_in[p,:]) + b_in[p]; f32 + bf16 copies --------
__global__ __launch_bounds__(256) void k_in(const float* __restrict__ hidden,
                                            const float* __restrict__ W_in,
                                            const float* __restrict__ b_in,
                                            float* __restrict__ h,
                                            ushort* __restrict__ hb) {
    __shared__ float4 hid[8 * 64];
    const int tid  = threadIdx.x;
    const int row0 = blockIdx.x * 8;
    const float4* src = (const float4*)(hidden + (size_t)row0 * HID);
    hid[tid]       = src[tid];
    hid[tid + 256] = src[tid + 256];
    __syncthreads();
    const int p = tid & 31;
    const int r = tid >> 5;
    const float4* w = (const float4*)(W_in + (size_t)p * HID);
    float acc = 0.f;
#pragma unroll
    for (int k = 0; k < 64; ++k) {
        float4 hv = hid[r * 64 + k];
        float4 wv = w[k];
        acc += hv.x * wv.x + hv.y * wv.y + hv.z * wv.z + hv.w * wv.w;
    }
    const float val = acc + b_in[p];
    h[(size_t)(row0 + r) * PAi + p]  = val;
    hb[(size_t)(row0 + r) * PAi + p] = f2bf(val);
}

// -------- Kernel 2: t[b,j,o,q] = sum_p h[b,j,p] * W_out[o, p*32+q]  (bf16 out) --------
#define RMID 16
__global__ __launch_bounds__(256) void k_mid(const float* __restrict__ h,
                                             const float* __restrict__ W_out,
                                             ushort* __restrict__ t) {
    __shared__ __attribute__((aligned(16))) float hst[PAi][RMID];
    const int tid  = threadIdx.x;
    const int row0 = blockIdx.x * RMID;
    for (int s = tid; s < RMID * PAi; s += 256) {
        const int r = s >> 5, p = s & 31;
        hst[p][r] = h[(size_t)(row0 + r) * PAi + p];
    }
    __syncthreads();
    const int qg = tid & 7;
    const int o1 = tid >> 3;
    const float4* W4 = (const float4*)W_out;
    float4 accA[RMID], accB[RMID];
#pragma unroll
    for (int r = 0; r < RMID; ++r) {
        accA[r] = float4{0, 0, 0, 0};
        accB[r] = float4{0, 0, 0, 0};
    }
#pragma unroll 2
    for (int p = 0; p < PAi; ++p) {
        const float4 wa = W4[(o1 * PAi + p) * 8 + qg];
        const float4 wb = W4[((o1 + 32) * PAi + p) * 8 + qg];
#pragma unroll
        for (int r4 = 0; r4 < RMID / 4; ++r4) {
            const float4 h4 = *(const float4*)&hst[p][r4 * 4];
            const float hr[4] = {h4.x, h4.y, h4.z, h4.w};
#pragma unroll
            for (int e = 0; e < 4; ++e) {
                const int r = r4 * 4 + e;
                accA[r].x += hr[e] * wa.x; accA[r].y += hr[e] * wa.y;
                accA[r].z += hr[e] * wa.z; accA[r].w += hr[e] * wa.w;
                accB[r].x += hr[e] * wb.x; accB[r].y += hr[e] * wb.y;
                accB[r].z += hr[e] * wb.z; accB[r].w += hr[e] * wb.w;
            }
        }
    }
#pragma unroll
    for (int r = 0; r < RMID; ++r) {
        ushort4 ua, ub;
        ua.x = f2bf(accA[r].x); ua.y = f2bf(accA[r].y); ua.z = f2bf(accA[r].z); ua.w = f2bf(accA[r].w);
        ub.x = f2bf(accB[r].x); ub.y = f2bf(accB[r].y); ub.z = f2bf(accB[r].z); ub.w = f2bf(accB[r].w);
        ushort* dst = t + (size_t)(row0 + r) * OO * PAi;
        *(ushort4*)(dst + (o1 * 8 + qg) * 4)        = ua;
        *(ushort4*)(dst + ((o1 + 32) * 8 + qg) * 4) = ub;
    }
}

// -------- Kernel 3: 1024-wide jo window (32 strips/row), 64 i-rows, t in regs --------
// 16 steps = 4 bands x 4 sub-chunks. Per step: {prefetch pv(s+1) | mfma -> LDS | barrier |
// consume: LDS rows + pw + bias -> 1KB NT store}. Rows get 4KB sequential runs per band;
// per-row fragmentation 128 -> 32 streams. t loaded once per block (16 frags in VGPRs).
#define WJO  1024
#define LSTR 260
__global__ __launch_bounds__(256, 4) void k_out(const ushort* __restrict__ t,   // bf16 [B][L*OO][PAi]
                                                const ushort* __restrict__ hb,  // bf16 [B][L][PAi]
                                                const float* __restrict__ pw,
                                                const float* __restrict__ b_out,
                                                float* __restrict__ out) {
    __shared__ float sA[16 * LSTR];  // 16.6 KB each
    __shared__ float sB[16 * LSTR];
    const int tid   = threadIdx.x;
    const int lane  = tid & 63;
    const int wave  = tid >> 6;
    const int b     = blockIdx.z;
    const int ibase = blockIdx.y * 64;
    const int jo0   = blockIdx.x * WJO;
    const int l15   = lane & 15;
    const int g     = lane >> 4;

    // 16 t fragments: sub-chunk cc, tile tt -> jo row jo0 + cc*256 + wave*64 + tt*16 + l15
    bf16x8 tf[16];
    {
        const ushort* tb0 = t + ((size_t)b * LL * OO + jo0 + wave * 64 + l15) * PAi + g * 8;
#pragma unroll
        for (int cc = 0; cc < 4; ++cc)
#pragma unroll
            for (int tt = 0; tt < 4; ++tt)
                tf[cc * 4 + tt] = *(const bf16x8*)(tb0 + (size_t)(cc * 256 + tt * 16) * PAi);
    }
    const f32x4 bo4 = *(const f32x4*)(b_out + ((lane * 4) & 63));

    auto loadH = [&](int it) -> bf16x8 {
        return *(const bf16x8*)(hb + ((size_t)(b * LL + ibase + it * 16 + l15)) * PAi + g * 8);
    };
    auto loadP = [&](int it, int cc, f32x4* pv) {
#pragma unroll
        for (int rr = 0; rr < 4; ++rr)
            pv[rr] = *(const f32x4*)(pw +
                ((size_t)(b * LL + ibase + it * 16 + wave * 4 + rr)) * (LL * OO)
                + jo0 + cc * 256 + lane * 4);
    };
    auto mfmaS = [&](int cc, const bf16x8 hfi, float* sbuf) {
#pragma unroll
        for (int tt = 0; tt < 4; ++tt) {
            f32x4 z = {0.f, 0.f, 0.f, 0.f};
            f32x4 a = __builtin_amdgcn_mfma_f32_16x16x32_bf16(tf[cc * 4 + tt], hfi, z, 0, 0, 0);
            *(f32x4*)&sbuf[l15 * LSTR + wave * 64 + tt * 16 + g * 4] = a;
        }
    };
    auto cons = [&](int it, int cc, const f32x4* pv, const float* sbuf) {
#pragma unroll
        for (int rr = 0; rr < 4; ++rr) {
            const f32x4 a4 = *(const f32x4*)&sbuf[(wave * 4 + rr) * LSTR + lane * 4];
            f32x4 res = a4 + bo4 + pv[rr];
            __builtin_nontemporal_store(res, (f32x4*)(out +
                ((size_t)(b * LL + ibase + it * 16 + wave * 4 + rr)) * (LL * OO)
                + jo0 + cc * 256 + lane * 4));
        }
    };

    bf16x8 hf[4];
    hf[0] = loadH(0);
    hf[1] = loadH(1);
    f32x4 pv[2][4];
    loadP(0, 0, pv[0]);

#pragma unroll
    for (int it = 0; it < 4; ++it) {
#pragma unroll
        for (int cc = 0; cc < 4; ++cc) {
            const int s = it * 4 + cc;
            if (cc == 0 && it < 2) hf[it + 2] = loadH(it + 2);          // hf prefetch, distance 8 steps
            if (s + 1 < 16) loadP((s + 1) >> 2, (s + 1) & 3, pv[(s + 1) & 1]);  // pv prefetch, distance 1
            mfmaS(cc, hf[it], (s & 1) ? sB : sA);
            barrier_lds();
            cons(it, cc, pv[s & 1], (s & 1) ? sB : sA);
        }
    }
}

extern "C" void kernel_launch(void* const* d_in, const int* in_sizes, int n_in,
                              void* d_out, int out_size, void* d_ws, size_t ws_size,
                              hipStream_t stream) {
    const float* hidden = (const float*)d_in[0];
    const float* pw     = (const float*)d_in[1];
    const float* W_in   = (const float*)d_in[2];
    const float* b_in   = (const float*)d_in[3];
    const float* W_out  = (const float*)d_in[4];
    const float* b_out  = (const float*)d_in[5];
    float* out = (float*)d_out;

    float*  h  = (float*)d_ws;                                // 65536 f32  (256 KB)
    ushort* hb = (ushort*)(h + (size_t)BB * LL * PAi);        // 65536 bf16 (128 KB)
    ushort* tb = hb + (size_t)BB * LL * PAi;                  // 4194304 bf16 (8 MB)

    k_in <<<dim3(BB * LL / 8), 256, 0, stream>>>(hidden, W_in, b_in, h, hb);
    k_mid<<<dim3(BB * LL / RMID), 256, 0, stream>>>(h, W_out, tb);
    // 32 jo-windows x 8 i-tiles(64) x 4 b = 1024 blocks = 4/CU
    k_out<<<dim3(LL * OO / WJO, LL / 64, BB), 256, 0, stream>>>(tb, hb, pw, b_out, out);
}

// Round 15
// 112.015 us; speedup vs baseline: 1.4456x; 1.4456x over previous
//
#include <hip/hip_runtime.h>

#define BB  4
#define LL  512
#define HID 256
#define PAi 32
#define OO  64

using bf16x8 = __attribute__((ext_vector_type(8))) short;
using f32x4  = __attribute__((ext_vector_type(4))) float;

__device__ inline ushort f2bf(float x) {
    union { float f; unsigned u; } v; v.f = x;
    unsigned r = (v.u + 0x7fff + ((v.u >> 16) & 1)) >> 16;  // RNE
    return (ushort)r;
}

// Relaxed barrier: order LDS traffic only; global prefetches stay in flight.
__device__ inline void barrier_lds() {
    asm volatile("s_waitcnt lgkmcnt(0)" ::: "memory");
    __builtin_amdgcn_s_barrier();
}

// -------- Kernel 1: h[b,l,p] = dot(hidden[b,l,:], W_in[p,:]) + b_in[p]; f32 + bf16 copies --------
__global__ __launch_bounds__(256) void k_in(const float* __restrict__ hidden,
                                            const float* __restrict__ W_in,
                                            const float* __restrict__ b_in,
                                            float* __restrict__ h,
                                            ushort* __restrict__ hb) {
    __shared__ float4 hid[8 * 64];
    const int tid  = threadIdx.x;
    const int row0 = blockIdx.x * 8;
    const float4* src = (const float4*)(hidden + (size_t)row0 * HID);
    hid[tid]       = src[tid];
    hid[tid + 256] = src[tid + 256];
    __syncthreads();
    const int p = tid & 31;
    const int r = tid >> 5;
    const float4* w = (const float4*)(W_in + (size_t)p * HID);
    float acc = 0.f;
#pragma unroll
    for (int k = 0; k < 64; ++k) {
        float4 hv = hid[r * 64 + k];
        float4 wv = w[k];
        acc += hv.x * wv.x + hv.y * wv.y + hv.z * wv.z + hv.w * wv.w;
    }
    const float val = acc + b_in[p];
    h[(size_t)(row0 + r) * PAi + p]  = val;
    hb[(size_t)(row0 + r) * PAi + p] = f2bf(val);
}

// -------- Kernel 2: t[b,j,o,q] = sum_p h[b,j,p] * W_out[o, p*32+q]  (bf16 out) --------
#define RMID 16
__global__ __launch_bounds__(256) void k_mid(const float* __restrict__ h,
                                             const float* __restrict__ W_out,
                                             ushort* __restrict__ t) {
    __shared__ __attribute__((aligned(16))) float hst[PAi][RMID];
    const int tid  = threadIdx.x;
    const int row0 = blockIdx.x * RMID;
    for (int s = tid; s < RMID * PAi; s += 256) {
        const int r = s >> 5, p = s & 31;
        hst[p][r] = h[(size_t)(row0 + r) * PAi + p];
    }
    __syncthreads();
    const int qg = tid & 7;
    const int o1 = tid >> 3;
    const float4* W4 = (const float4*)W_out;
    float4 accA[RMID], accB[RMID];
#pragma unroll
    for (int r = 0; r < RMID; ++r) {
        accA[r] = float4{0, 0, 0, 0};
        accB[r] = float4{0, 0, 0, 0};
    }
#pragma unroll 2
    for (int p = 0; p < PAi; ++p) {
        const float4 wa = W4[(o1 * PAi + p) * 8 + qg];
        const float4 wb = W4[((o1 + 32) * PAi + p) * 8 + qg];
#pragma unroll
        for (int r4 = 0; r4 < RMID / 4; ++r4) {
            const float4 h4 = *(const float4*)&hst[p][r4 * 4];
            const float hr[4] = {h4.x, h4.y, h4.z, h4.w};
#pragma unroll
            for (int e = 0; e < 4; ++e) {
                const int r = r4 * 4 + e;
                accA[r].x += hr[e] * wa.x; accA[r].y += hr[e] * wa.y;
                accA[r].z += hr[e] * wa.z; accA[r].w += hr[e] * wa.w;
                accB[r].x += hr[e] * wb.x; accB[r].y += hr[e] * wb.y;
                accB[r].z += hr[e] * wb.z; accB[r].w += hr[e] * wb.w;
            }
        }
    }
#pragma unroll
    for (int r = 0; r < RMID; ++r) {
        ushort4 ua, ub;
        ua.x = f2bf(accA[r].x); ua.y = f2bf(accA[r].y); ua.z = f2bf(accA[r].z); ua.w = f2bf(accA[r].w);
        ub.x = f2bf(accB[r].x); ub.y = f2bf(accB[r].y); ub.z = f2bf(accB[r].z); ub.w = f2bf(accB[r].w);
        ushort* dst = t + (size_t)(row0 + r) * OO * PAi;
        *(ushort4*)(dst + (o1 * 8 + qg) * 4)        = ua;
        *(ushort4*)(dst + ((o1 + 32) * 8 + qg) * 4) = ub;
    }
}

// -------- Kernel 3: 512-wide jo window (64 strips/row), 128 i-rows, t in regs (no spill) --------
// tf[8] = 32 VGPRs (r14's tf[16]=64 spilled -> scratch traffic; this is the spill-free size).
// 8 bands x 2 sub-chunks = 16 steps; per step {pv prefetch s+1 | mfma -> LDS | barrier |
// consume: LDS rows + pw + bias -> 1KB NT store}. Per-row runs 2KB; 64 streams/row.
#define WJO  512
#define IROWS 128
#define LSTR 260
__global__ __launch_bounds__(256, 4) void k_out(const ushort* __restrict__ t,   // bf16 [B][L*OO][PAi]
                                                const ushort* __restrict__ hb,  // bf16 [B][L][PAi]
                                                const float* __restrict__ pw,
                                                const float* __restrict__ b_out,
                                                float* __restrict__ out) {
    __shared__ float sA[16 * LSTR];  // 16.6 KB each
    __shared__ float sB[16 * LSTR];
    const int tid   = threadIdx.x;
    const int lane  = tid & 63;
    const int wave  = tid >> 6;
    const int b     = blockIdx.z;
    const int ibase = blockIdx.y * IROWS;
    const int jo0   = blockIdx.x * WJO;
    const int l15   = lane & 15;
    const int g     = lane >> 4;

    // 8 t fragments: sub-chunk cc (0..1), tile tt -> jo = jo0 + cc*256 + wave*64 + tt*16 + l15
    bf16x8 tf[8];
    {
        const ushort* tb0 = t + ((size_t)b * LL * OO + jo0 + wave * 64 + l15) * PAi + g * 8;
#pragma unroll
        for (int cc = 0; cc < 2; ++cc)
#pragma unroll
            for (int tt = 0; tt < 4; ++tt)
                tf[cc * 4 + tt] = *(const bf16x8*)(tb0 + (size_t)(cc * 256 + tt * 16) * PAi);
    }
    const f32x4 bo4 = *(const f32x4*)(b_out + ((lane * 4) & 63));

    auto loadH = [&](int it) -> bf16x8 {
        return *(const bf16x8*)(hb + ((size_t)(b * LL + ibase + it * 16 + l15)) * PAi + g * 8);
    };
    auto loadP = [&](int it, int cc, f32x4* pv) {
#pragma unroll
        for (int rr = 0; rr < 4; ++rr)
            pv[rr] = *(const f32x4*)(pw +
                ((size_t)(b * LL + ibase + it * 16 + wave * 4 + rr)) * (LL * OO)
                + jo0 + cc * 256 + lane * 4);
    };
    auto mfmaS = [&](int cc, const bf16x8 hfi, float* sbuf) {
#pragma unroll
        for (int tt = 0; tt < 4; ++tt) {
            f32x4 z = {0.f, 0.f, 0.f, 0.f};
            f32x4 a = __builtin_amdgcn_mfma_f32_16x16x32_bf16(tf[cc * 4 + tt], hfi, z, 0, 0, 0);
            *(f32x4*)&sbuf[l15 * LSTR + wave * 64 + tt * 16 + g * 4] = a;
        }
    };
    auto cons = [&](int it, int cc, const f32x4* pv, const float* sbuf) {
#pragma unroll
        for (int rr = 0; rr < 4; ++rr) {
            const f32x4 a4 = *(const f32x4*)&sbuf[(wave * 4 + rr) * LSTR + lane * 4];
            f32x4 res = a4 + bo4 + pv[rr];
            __builtin_nontemporal_store(res, (f32x4*)(out +
                ((size_t)(b * LL + ibase + it * 16 + wave * 4 + rr)) * (LL * OO)
                + jo0 + cc * 256 + lane * 4));
        }
    };

    bf16x8 hf0 = loadH(0), hf1 = loadH(1);
    f32x4 pv[2][4];
    loadP(0, 0, pv[0]);

#pragma unroll
    for (int it = 0; it < IROWS / 16; ++it) {
#pragma unroll
        for (int cc = 0; cc < 2; ++cc) {
            const int s = it * 2 + cc;
            if (s + 1 < IROWS / 8) loadP((s + 1) >> 1, (s + 1) & 1, pv[(s + 1) & 1]);
            mfmaS(cc, (it & 1) ? hf1 : hf0, (s & 1) ? sB : sA);
            // refill the hf slot after its band's last MFMA (static under full unroll)
            if (cc == 1 && it + 2 < IROWS / 16) {
                if (it & 1) hf1 = loadH(it + 2);
                else        hf0 = loadH(it + 2);
            }
            barrier_lds();
            cons(it, cc, pv[s & 1], (s & 1) ? sB : sA);
        }
    }
}

extern "C" void kernel_launch(void* const* d_in, const int* in_sizes, int n_in,
                              void* d_out, int out_size, void* d_ws, size_t ws_size,
                              hipStream_t stream) {
    const float* hidden = (const float*)d_in[0];
    const float* pw     = (const float*)d_in[1];
    const float* W_in   = (const float*)d_in[2];
    const float* b_in   = (const float*)d_in[3];
    const float* W_out  = (const float*)d_in[4];
    const float* b_out  = (const float*)d_in[5];
    float* out = (float*)d_out;

    float*  h  = (float*)d_ws;                                // 65536 f32  (256 KB)
    ushort* hb = (ushort*)(h + (size_t)BB * LL * PAi);        // 65536 bf16 (128 KB)
    ushort* tb = hb + (size_t)BB * LL * PAi;                  // 4194304 bf16 (8 MB)

    k_in <<<dim3(BB * LL / 8), 256, 0, stream>>>(hidden, W_in, b_in, h, hb);
    k_mid<<<dim3(BB * LL / RMID), 256, 0, stream>>>(h, W_out, tb);
    // 64 jo-windows x 4 i-tiles(128) x 4 b = 1024 blocks = 4/CU
    k_out<<<dim3(LL * OO / WJO, LL / IROWS, BB), 256, 0, stream>>>(tb, hb, pw, b_out, out);
}